// Round 12
// baseline (22.151 us; speedup 1.0000x reference)
//
#include <hip/hip_runtime.h>
#include <math.h>

// RBF layer: out[b,u] = exp(-gamma*||x_b - c_u||^2), B=8192, U=2048, DIM=32, f32.
//
// out = exp2(kg*||x||^2 + kg*||c||^2 + m2*(x.c)); x.c via bf16 hi/lo split
// (3x mfma_f32_16x16x32_bf16, K=32=DIM). Norms full f32. Verified R4-R11.
//
// R11 post-mortem: WAR ping-pong null. Six levers tested; last unisolated
// path variable = store SEGMENT SIZE (ours 64B x16 per instr vs 1KB runs of
// every 6.3TB/s reference). R12: wave owns 16 rows x 128 cols; epilogue
// bounces through wave-PRIVATE 8KB LDS (no barriers, slot-rotate swizzle),
// stores become 8 instrs x (2 rows x 512B contiguous). Same bytes, same
// instruction count, 8x bigger segments. Everything else = R10 (slab
// mapping, prefetch, swapped MFMA operands).

#define BATCH   8192
#define UNITS   2048
#define DIM     32
#define BM      64
#define BN      128
#define THREADS 256
#define NXCD    8
#define ITERS   4      // 8 xcd * 4 slot * 4 iter * 64 rows = 8192

typedef __attribute__((ext_vector_type(8))) short s16x8;   // 8 bf16
typedef __attribute__((ext_vector_type(4))) float f32x4;

static __device__ __forceinline__ unsigned bf16_rne(float v) {
    unsigned u = __builtin_bit_cast(unsigned, v);
    return (u + 0x7FFFu + ((u >> 16) & 1u)) >> 16;   // round-to-nearest-even
}

static __device__ __forceinline__ void load8(const float* __restrict__ p, float* v) {
    float4 t0 = *reinterpret_cast<const float4*>(p);
    float4 t1 = *reinterpret_cast<const float4*>(p + 4);
    v[0] = t0.x; v[1] = t0.y; v[2] = t0.z; v[3] = t0.w;
    v[4] = t1.x; v[5] = t1.y; v[6] = t1.z; v[7] = t1.w;
}

static __device__ __forceinline__ void split8(const float* v, s16x8& hi, s16x8& lo) {
#pragma unroll
    for (int j = 0; j < 8; ++j) {
        unsigned h = bf16_rne(v[j]);
        float hf = __builtin_bit_cast(float, h << 16);
        unsigned l = bf16_rne(v[j] - hf);
        hi[j] = (short)h;
        lo[j] = (short)l;
    }
}

__global__ __launch_bounds__(THREADS, 2) void rbf_stream(
    const float* __restrict__ x,
    const float* __restrict__ centers,
    const float* __restrict__ gamma,
    float* __restrict__ out)
{
    // wave-private bounce tiles: [wave][row 0..15][slot 0..31] float4 (32KB)
    __shared__ __align__(16) f32x4 s_t[4][16][32];

    const int tid  = threadIdx.x;
    const int w    = tid >> 6;        // wave 0..3: rows w*16..w*16+15
    const int lane = tid & 63;
    const int l16  = lane & 15;
    const int kq   = lane >> 4;       // 0..3

    // ---- XCD-slab block mapping (R10) ----
    const int bid = blockIdx.x;       // 0..511
    const int xcd = bid & (NXCD - 1);
    const int rlo = bid >> 3;
    const int cb  = rlo & 15;         // col block 0..15
    const int sb  = rlo >> 4;         // row slot 0..3
    const int c0  = cb * BN;

    const float kg = -gamma[0] * 1.4426950408889634f;  // -g*log2(e)
    const float m2 = -2.0f * kg;

    // ---- prologue: ALL 8 center tiles per wave + kg*||c||^2 ----
    s16x8 b_hi[8], b_lo[8];
    float kgcnq[8][4];
#pragma unroll
    for (int n = 0; n < 8; ++n) {
        float v[8];
        load8(centers + (size_t)(c0 + n * 16 + l16) * DIM + kq * 8, v);
        split8(v, b_hi[n], b_lo[n]);
        float pn = 0.f;
#pragma unroll
        for (int j = 0; j < 8; ++j) pn = fmaf(v[j], v[j], pn);
        pn += __shfl_xor(pn, 16);
        pn += __shfl_xor(pn, 32);     // lane holds ||c_{n*16+l16}||^2
#pragma unroll
        for (int j = 0; j < 4; ++j)
            kgcnq[n][j] = kg * __shfl(pn, kq * 4 + j);
    }

    // ---- software-pipelined x loads (16 rows per wave) ----
    float xf[2][8];
    load8(x + (size_t)((xcd * 16 + sb) * BM + w * 16 + l16) * DIM + kq * 8, xf[0]);

#pragma unroll
    for (int k = 0; k < ITERS; ++k) {
        const int cur = k & 1;
        const int r0  = (xcd * 16 + k * 4 + sb) * BM;

        if (k + 1 < ITERS) {          // prefetch next row-tile
            const int r1 = (xcd * 16 + (k + 1) * 4 + sb) * BM;
            load8(x + (size_t)(r1 + w * 16 + l16) * DIM + kq * 8, xf[cur ^ 1]);
        }

        // convert + per-row norm (wave-local)
        s16x8 a_hi, a_lo;
        split8(xf[cur], a_hi, a_lo);
        float pn = 0.f;
#pragma unroll
        for (int j = 0; j < 8; ++j) pn = fmaf(xf[cur][j], xf[cur][j], pn);
        pn += __shfl_xor(pn, 16);
        pn += __shfl_xor(pn, 32);     // full norm of row l16
        const float kgxn = kg * pn;

        // MFMA (swapped: D = c . x^T) + exp -> wave-private LDS (swizzled)
#pragma unroll
        for (int n = 0; n < 8; ++n) {
            f32x4 acc = {0.f, 0.f, 0.f, 0.f};
            acc = __builtin_amdgcn_mfma_f32_16x16x32_bf16(b_lo[n], a_hi, acc, 0, 0, 0);
            acc = __builtin_amdgcn_mfma_f32_16x16x32_bf16(b_hi[n], a_lo, acc, 0, 0, 0);
            acc = __builtin_amdgcn_mfma_f32_16x16x32_bf16(b_hi[n], a_hi, acc, 0, 0, 0);

            f32x4 o;
            o[0] = __builtin_amdgcn_exp2f(fmaf(m2, acc[0], kgxn + kgcnq[n][0]));
            o[1] = __builtin_amdgcn_exp2f(fmaf(m2, acc[1], kgxn + kgcnq[n][1]));
            o[2] = __builtin_amdgcn_exp2f(fmaf(m2, acc[2], kgxn + kgcnq[n][2]));
            o[3] = __builtin_amdgcn_exp2f(fmaf(m2, acc[3], kgxn + kgcnq[n][3]));

            const int s = ((n * 4 + kq) + l16 * 4) & 31;   // rotate swizzle
            s_t[w][l16][s] = o;                             // ds_write_b128
        }

        // read back in store layout + 2x512B-contiguous stores (no barrier:
        // wave-private region, DS ops are in-order per wave)
#pragma unroll
        for (int p = 0; p < 8; ++p) {
            const int row = 2 * p + (lane >> 5);
            const int sl  = ((lane & 31) + row * 4) & 31;   // same swizzle
            f32x4 v = s_t[w][row][sl];                      // ds_read_b128
            float* op = out + (size_t)(r0 + w * 16 + row) * UNITS
                            + c0 + (lane & 31) * 4;
            *reinterpret_cast<f32x4*>(op) = v;
        }
    }
}

extern "C" void kernel_launch(void* const* d_in, const int* in_sizes, int n_in,
                              void* d_out, int out_size, void* d_ws, size_t ws_size,
                              hipStream_t stream)
{
    const float* x       = (const float*)d_in[0];
    const float* centers = (const float*)d_in[1];
    const float* gamma   = (const float*)d_in[2];
    float* out           = (float*)d_out;

    dim3 grid(512);                   // 1D; slab mapping in-kernel
    dim3 block(THREADS);
    rbf_stream<<<grid, block, 0, stream>>>(x, centers, gamma, out);
}

// Round 13
// 21.790 us; speedup vs baseline: 1.0166x; 1.0166x over previous
//
#include <hip/hip_runtime.h>
#include <math.h>

// RBF layer: out[b,u] = exp(-gamma*||x_b - c_u||^2), B=8192, U=2048, DIM=32, f32.
//
// out = exp2(kg*||x||^2 + kg*||c||^2 + m2*(x.c)); x.c via bf16 hi/lo split
// (3x mfma_f32_16x16x32_bf16, K=32=DIM). Norms full f32. Verified R4-R12.
//
// R12 post-mortem: big-segment stores null -> store path fully exonerated
// (shape/segments/L2-policy/WAR/page-locality all null). R9 profile says
// LATENCY-bound (VALU 9.7%, HBM 24%, occupancy 18.6%: all idle). R7's "TLP
// refuted" was confounded: doubling waves also halved ITERS (prologue
// amortization). R13: TLP at CONSTANT prologue:work ratio. Wave footprint
// halved (BN 64, 4 n-tiles/wave -> prologue & per-iter chains halve),
// grid doubled (1024 blocks = 16 waves/CU), ITERS=4 + R10 slab walk kept.

#define BATCH   8192
#define UNITS   2048
#define DIM     32
#define BM      64
#define BN      64
#define THREADS 256
#define NXCD    8
#define ITERS   4      // 8 xcd * 4 slot * 4 iter * 64 rows = 8192

typedef __attribute__((ext_vector_type(8))) short s16x8;   // 8 bf16
typedef __attribute__((ext_vector_type(4))) float f32x4;

static __device__ __forceinline__ unsigned bf16_rne(float v) {
    unsigned u = __builtin_bit_cast(unsigned, v);
    return (u + 0x7FFFu + ((u >> 16) & 1u)) >> 16;   // round-to-nearest-even
}

static __device__ __forceinline__ void load8(const float* __restrict__ p, float* v) {
    float4 t0 = *reinterpret_cast<const float4*>(p);
    float4 t1 = *reinterpret_cast<const float4*>(p + 4);
    v[0] = t0.x; v[1] = t0.y; v[2] = t0.z; v[3] = t0.w;
    v[4] = t1.x; v[5] = t1.y; v[6] = t1.z; v[7] = t1.w;
}

static __device__ __forceinline__ void split8(const float* v, s16x8& hi, s16x8& lo) {
#pragma unroll
    for (int j = 0; j < 8; ++j) {
        unsigned h = bf16_rne(v[j]);
        float hf = __builtin_bit_cast(float, h << 16);
        unsigned l = bf16_rne(v[j] - hf);
        hi[j] = (short)h;
        lo[j] = (short)l;
    }
}

__global__ __launch_bounds__(THREADS, 4) void rbf_stream(
    const float* __restrict__ x,
    const float* __restrict__ centers,
    const float* __restrict__ gamma,
    float* __restrict__ out)
{
    const int tid  = threadIdx.x;
    const int w    = tid >> 6;        // wave 0..3: rows w*16..w*16+15 of tile
    const int lane = tid & 63;
    const int l16  = lane & 15;
    const int kq   = lane >> 4;       // 0..3

    // ---- XCD-slab block mapping ----
    const int bid  = blockIdx.x;      // 0..1023
    const int xcd  = bid & (NXCD - 1);
    const int rest = bid >> 3;        // 0..127
    const int cb   = rest & 31;       // col block 0..31
    const int sb   = rest >> 5;       // row slot 0..3
    const int c0   = cb * BN;

    const float kg = -gamma[0] * 1.4426950408889634f;  // -g*log2(e)
    const float m2 = -2.0f * kg;

    // ---- prologue: 4 center tiles per wave + kg*||c||^2 ----
    s16x8 b_hi[4], b_lo[4];
    float kgcnq[4][4];
#pragma unroll
    for (int n = 0; n < 4; ++n) {
        float v[8];
        load8(centers + (size_t)(c0 + n * 16 + l16) * DIM + kq * 8, v);
        split8(v, b_hi[n], b_lo[n]);
        float pn = 0.f;
#pragma unroll
        for (int j = 0; j < 8; ++j) pn = fmaf(v[j], v[j], pn);
        pn += __shfl_xor(pn, 16);
        pn += __shfl_xor(pn, 32);     // lane holds ||c_{n*16+l16}||^2
#pragma unroll
        for (int j = 0; j < 4; ++j)
            kgcnq[n][j] = kg * __shfl(pn, kq * 4 + j);
    }

    // ---- software-pipelined x loads (16 rows per wave) ----
    float xf[2][8];
    load8(x + (size_t)((xcd * 16 + sb) * BM + w * 16 + l16) * DIM + kq * 8, xf[0]);

#pragma unroll
    for (int k = 0; k < ITERS; ++k) {
        const int cur = k & 1;
        const int r0  = (xcd * 16 + k * 4 + sb) * BM;

        if (k + 1 < ITERS) {          // prefetch next row-tile
            const int r1 = (xcd * 16 + (k + 1) * 4 + sb) * BM;
            load8(x + (size_t)(r1 + w * 16 + l16) * DIM + kq * 8, xf[cur ^ 1]);
        }

        // convert + per-row norm (wave-local, no LDS)
        s16x8 a_hi, a_lo;
        split8(xf[cur], a_hi, a_lo);
        float pn = 0.f;
#pragma unroll
        for (int j = 0; j < 8; ++j) pn = fmaf(xf[cur][j], xf[cur][j], pn);
        pn += __shfl_xor(pn, 16);
        pn += __shfl_xor(pn, 32);     // full norm of row l16
        const float kgxn = kg * pn;

        // MFMA (swapped: D = c . x^T) + epilogue, per-tile dwordx4 stores
#pragma unroll
        for (int n = 0; n < 4; ++n) {
            f32x4 acc = {0.f, 0.f, 0.f, 0.f};
            acc = __builtin_amdgcn_mfma_f32_16x16x32_bf16(b_lo[n], a_hi, acc, 0, 0, 0);
            acc = __builtin_amdgcn_mfma_f32_16x16x32_bf16(b_hi[n], a_lo, acc, 0, 0, 0);
            acc = __builtin_amdgcn_mfma_f32_16x16x32_bf16(b_hi[n], a_hi, acc, 0, 0, 0);

            float4 o;
            o.x = __builtin_amdgcn_exp2f(fmaf(m2, acc[0], kgxn + kgcnq[n][0]));
            o.y = __builtin_amdgcn_exp2f(fmaf(m2, acc[1], kgxn + kgcnq[n][1]));
            o.z = __builtin_amdgcn_exp2f(fmaf(m2, acc[2], kgxn + kgcnq[n][2]));
            o.w = __builtin_amdgcn_exp2f(fmaf(m2, acc[3], kgxn + kgcnq[n][3]));

            float* op = out + (size_t)(r0 + w * 16 + l16) * UNITS
                            + (c0 + n * 16 + kq * 4);
            *reinterpret_cast<float4*>(op) = o;
        }
    }
}

extern "C" void kernel_launch(void* const* d_in, const int* in_sizes, int n_in,
                              void* d_out, int out_size, void* d_ws, size_t ws_size,
                              hipStream_t stream)
{
    const float* x       = (const float*)d_in[0];
    const float* centers = (const float*)d_in[1];
    const float* gamma   = (const float*)d_in[2];
    float* out           = (float*)d_out;

    dim3 grid(1024);                  // 1D; slab mapping in-kernel
    dim3 block(THREADS);
    rbf_stream<<<grid, block, 0, stream>>>(x, centers, gamma, out);
}